// Round 3
// baseline (1042.062 us; speedup 1.0000x reference)
//
#include <hip/hip_runtime.h>

#define N_NODES 50000
#define N_EDGES 300000
#define DIM 256
#define FEAT 1024
#define NCLS 40

typedef unsigned short u16;
typedef __attribute__((ext_vector_type(8))) short short8;
typedef __attribute__((ext_vector_type(4))) float float4v;

__device__ __forceinline__ float bf2f(u16 u) {
  union { float f; unsigned v; } x; x.v = ((unsigned)u) << 16; return x.f;
}
__device__ __forceinline__ u16 f2bf(float f) {
  union { float f; unsigned v; } x; x.f = f;
  unsigned r = 0x7fffu + ((x.v >> 16) & 1u);
  return (u16)((x.v + r) >> 16);
}
// f32flag: 1 -> buffer is fp32, 0 -> buffer is bf16
__device__ __forceinline__ float flexload(const void* p, size_t i, int f32) {
  return f32 ? ((const float*)p)[i] : bf2f(((const u16*)p)[i]);
}
__device__ __forceinline__ void flexstore(void* p, size_t i, int f32, float v) {
  if (f32) ((float*)p)[i] = v;
  else ((u16*)p)[i] = f2bf(v);
}

// ---------------- dtype sniff ----------------
// Interpret feat's even-index u16s as bf16. True-bf16 data: ~all values in
// (1e-5, 64). fp32 data read as bf16 pairs: even u16s are fp32 mantissa bits
// -> random exponents, ~9% in range. Writes dflag[0]=1 if fp32.
__global__ __launch_bounds__(256) void k_sniff(const u16* __restrict__ feat,
                                               int* __restrict__ dflag) {
  __shared__ int cnt[256];
  int t = threadIdx.x;
  int ok = 0;
  for (int j = 0; j < 4; ++j) {
    float v = bf2f(feat[(size_t)(t * 4 + j) * 2]);
    float a = fabsf(v);
    if (a < 64.0f && a > 1e-5f) ok++;
  }
  cnt[t] = ok;
  __syncthreads();
  for (int off = 128; off > 0; off >>= 1) {
    if (t < off) cnt[t] += cnt[t + off];
    __syncthreads();
  }
  if (t == 0) dflag[0] = (cnt[0] < 700) ? 1 : 0;
}

__global__ void k_setflag(int* dflag, int v) { dflag[0] = v; }

__global__ void k_filldiag(void* out, int n, float val, const int* __restrict__ dflag) {
  int i = blockIdx.x * blockDim.x + threadIdx.x;
  if (i < n) flexstore(out, i, dflag[0], val);
}

// ---------------- graph prep ----------------

__global__ void k_zero(unsigned* p, int n) {
  int i = blockIdx.x * blockDim.x + threadIdx.x;
  if (i < n) p[i] = 0u;
}

__global__ void k_deg(const int* __restrict__ src, const int* __restrict__ dst,
                      float* __restrict__ degf, int* __restrict__ degi, int e) {
  int i = blockIdx.x * blockDim.x + threadIdx.x;
  if (i < e) {
    atomicAdd(&degf[src[i]], 1.0f);
    atomicAdd(&degi[dst[i]], 1);
  }
}

__global__ void k_norm(const float* __restrict__ degf, const int* __restrict__ degi,
                       float* __restrict__ ns, float* __restrict__ nd, int n) {
  int i = blockIdx.x * blockDim.x + threadIdx.x;
  if (i < n) {
    ns[i] = rsqrtf(fmaxf(degf[i], 1.0f));
    nd[i] = rsqrtf(fmaxf((float)degi[i], 1.0f));
  }
}

__global__ __launch_bounds__(1024) void k_scan(const int* __restrict__ counts,
                                               int* __restrict__ row_start,
                                               int* __restrict__ cursor, int n) {
  __shared__ int wsum[16];
  __shared__ int carry_s;
  int t = threadIdx.x;
  int lane = t & 63, wv = t >> 6;
  if (t == 0) carry_s = 0;
  __syncthreads();
  for (int base = 0; base < n; base += 4096) {
    int i0 = base + t * 4;
    int v0 = 0, v1 = 0, v2 = 0, v3 = 0;
    if (i0 + 3 < n) {
      int4 c4 = *(const int4*)&counts[i0];
      v0 = c4.x; v1 = c4.y; v2 = c4.z; v3 = c4.w;
    } else {
      if (i0 < n) v0 = counts[i0];
      if (i0 + 1 < n) v1 = counts[i0 + 1];
      if (i0 + 2 < n) v2 = counts[i0 + 2];
      if (i0 + 3 < n) v3 = counts[i0 + 3];
    }
    int s = v0 + v1 + v2 + v3;
    int sc = s;
#pragma unroll
    for (int off = 1; off < 64; off <<= 1) {
      int u = __shfl_up(sc, off, 64);
      if (lane >= off) sc += u;
    }
    if (lane == 63) wsum[wv] = sc;
    __syncthreads();
    if (wv == 0) {
      int w_ = (lane < 16) ? wsum[lane] : 0;
#pragma unroll
      for (int off = 1; off < 16; off <<= 1) {
        int u = __shfl_up(w_, off, 64);
        if (lane >= off) w_ += u;
      }
      if (lane < 16) wsum[lane] = w_;
    }
    __syncthreads();
    int wbase = (wv == 0) ? 0 : wsum[wv - 1];
    int carry = carry_s;
    int excl = carry + wbase + (sc - s);
    if (i0 < n)     { int p = excl;                row_start[i0] = p;     cursor[i0] = p; }
    if (i0 + 1 < n) { int p = excl + v0;           row_start[i0 + 1] = p; cursor[i0 + 1] = p; }
    if (i0 + 2 < n) { int p = excl + v0 + v1;      row_start[i0 + 2] = p; cursor[i0 + 2] = p; }
    if (i0 + 3 < n) { int p = excl + v0 + v1 + v2; row_start[i0 + 3] = p; cursor[i0 + 3] = p; }
    __syncthreads();
    if (t == 1023) carry_s = carry + wbase + sc;
    __syncthreads();
  }
  if (t == 0) row_start[n] = carry_s;
}

__global__ void k_scatter(const int* __restrict__ src, const int* __restrict__ dst,
                          int* __restrict__ cursor, int* __restrict__ csr_src, int e) {
  int i = blockIdx.x * blockDim.x + threadIdx.x;
  if (i < e) {
    int pos = atomicAdd(&cursor[dst[i]], 1);
    csr_src[pos] = src[i];
  }
}

__global__ void k_transpose(const void* __restrict__ w, u16* __restrict__ wt,
                            int K, int Ncols, const int* __restrict__ dflag) {
  int f = dflag[0];
  int i = blockIdx.x * blockDim.x + threadIdx.x;
  if (i < K * Ncols) {
    int k = i / Ncols;
    int c = i - k * Ncols;
    wt[c * K + k] = f2bf(flexload(w, i, f));
  }
}

// ---------------- GEMM: C[M,Nc] = A[M,K] @ B + bias, Bt given as [Nc,K] bf16 ----------------
// 128x128 tile, 4 waves (2x2), each wave 64x64 via 4x4 of mfma 16x16x32 bf16, BK=64.

__global__ __launch_bounds__(256) void k_gemm(
    const void* __restrict__ A, const u16* __restrict__ Bt,
    const void* __restrict__ bias, void* __restrict__ Cmat,
    int M, int K, int Ncols, int a_flex, int c_flex,
    const int* __restrict__ dflag) {
  __shared__ __align__(16) u16 As[64 * 128];  // [kq(8)][m(128)][8]
  __shared__ __align__(16) u16 Bs[64 * 128];  // [kq(8)][n(128)][8]

  const int f = dflag[0];
  const int af = a_flex & f;  // A is fp32
  const int cf = c_flex & f;  // C store fp32

  const int tid = threadIdx.x;
  const int lane = tid & 63;
  const int wv = tid >> 6;
  const int wm = (wv >> 1) * 64;
  const int wn = (wv & 1) * 64;
  const int quad = lane >> 4;
  const int l15 = lane & 15;
  const int rowBase = blockIdx.x * 128;
  const int colBase = blockIdx.y * 128;

  float4v acc[4][4];
#pragma unroll
  for (int a = 0; a < 4; ++a)
#pragma unroll
    for (int b = 0; b < 4; ++b) {
      acc[a][b][0] = 0.f; acc[a][b][1] = 0.f; acc[a][b][2] = 0.f; acc[a][b][3] = 0.f;
    }

  for (int k0 = 0; k0 < K; k0 += 64) {
    __syncthreads();
#pragma unroll
    for (int r = 0; r < 4; ++r) {
      int j = r * 256 + tid;
      int kq = j >> 7;
      int ml = j & 127;
      int grow = rowBase + ml;
      if (grow >= M) grow = M - 1;
      size_t abase = (size_t)grow * K + k0 + kq * 8;
      if (af) {
        const float* Af = (const float*)A;
        float4 lo = *(const float4*)&Af[abase];
        float4 hi = *(const float4*)&Af[abase + 4];
        u16* d = &As[j * 8];
        d[0] = f2bf(lo.x); d[1] = f2bf(lo.y); d[2] = f2bf(lo.z); d[3] = f2bf(lo.w);
        d[4] = f2bf(hi.x); d[5] = f2bf(hi.y); d[6] = f2bf(hi.z); d[7] = f2bf(hi.w);
      } else {
        const u16* Au = (const u16*)A;
        *(uint4*)&As[j * 8] = *(const uint4*)&Au[abase];
      }
      *(uint4*)&Bs[j * 8] = *(const uint4*)&Bt[(size_t)(colBase + ml) * K + k0 + kq * 8];
    }
    __syncthreads();
#pragma unroll
    for (int ks = 0; ks < 2; ++ks) {
      short8 afr[4], bfr[4];
#pragma unroll
      for (int t = 0; t < 4; ++t) {
        int kq = ks * 4 + quad;
        afr[t] = *(const short8*)&As[(kq * 128 + wm + t * 16 + l15) * 8];
        bfr[t] = *(const short8*)&Bs[(kq * 128 + wn + t * 16 + l15) * 8];
      }
#pragma unroll
      for (int mt = 0; mt < 4; ++mt)
#pragma unroll
        for (int nt = 0; nt < 4; ++nt)
          acc[mt][nt] = __builtin_amdgcn_mfma_f32_16x16x32_bf16(
              afr[mt], bfr[nt], acc[mt][nt], 0, 0, 0);
    }
  }

#pragma unroll
  for (int nt = 0; nt < 4; ++nt) {
    int col = colBase + wn + nt * 16 + l15;
    float bv = flexload(bias, col, f);
#pragma unroll
    for (int mt = 0; mt < 4; ++mt) {
#pragma unroll
      for (int r = 0; r < 4; ++r) {
        int row = rowBase + wm + mt * 16 + quad * 4 + r;
        if (row < M) {
          float v = acc[mt][nt][r] + bv;
          if (cf) ((float*)Cmat)[(size_t)row * Ncols + col] = v;
          else ((u16*)Cmat)[(size_t)row * Ncols + col] = f2bf(v);
        }
      }
    }
  }
}

// ---------------- SpMM (internal bf16) ----------------

__global__ __launch_bounds__(256) void k_spmm(
    const u16* __restrict__ x, u16* __restrict__ y,
    const int* __restrict__ row_start, const int* __restrict__ csr_src,
    const float* __restrict__ ns, const float* __restrict__ nd, int n) {
  int wid = (blockIdx.x * blockDim.x + threadIdx.x) >> 6;
  int lane = threadIdx.x & 63;
  if (wid >= n) return;
  int e0 = row_start[wid];
  int e1 = row_start[wid + 1];
  int c = lane * 4;
  float a0 = 0.f, a1 = 0.f, a2 = 0.f, a3 = 0.f;
  for (int e = e0; e < e1; ++e) {
    int s = csr_src[e];
    float w = ns[s];
    uint2 v = *(const uint2*)&x[(size_t)s * DIM + c];
    a0 += w * bf2f((u16)(v.x & 0xffffu));
    a1 += w * bf2f((u16)(v.x >> 16));
    a2 += w * bf2f((u16)(v.y & 0xffffu));
    a3 += w * bf2f((u16)(v.y >> 16));
  }
  float wd = nd[wid];
  uint2 o;
  o.x = (unsigned)f2bf(a0 * wd) | ((unsigned)f2bf(a1 * wd) << 16);
  o.y = (unsigned)f2bf(a2 * wd) | ((unsigned)f2bf(a3 * wd) << 16);
  *(uint2*)&y[(size_t)wid * DIM + c] = o;
}

// ---------------- BatchNorm (training stats) + ELU, internal bf16 ----------------

__global__ __launch_bounds__(256) void k_bnstats(const u16* __restrict__ x,
                                                 float* __restrict__ stats, int nrows) {
  int t = threadIdx.x;
  float s = 0.f, s2 = 0.f;
  for (int r = blockIdx.x; r < nrows; r += gridDim.x) {
    float v = bf2f(x[(size_t)r * DIM + t]);
    s += v;
    s2 += v * v;
  }
  atomicAdd(&stats[t], s);
  atomicAdd(&stats[DIM + t], s2);
}

__global__ __launch_bounds__(256) void k_bnapply(u16* __restrict__ x,
                                                 const float* __restrict__ stats,
                                                 const void* __restrict__ gamma,
                                                 const void* __restrict__ beta, int nrows,
                                                 const int* __restrict__ dflag) {
  int f = dflag[0];
  int t = threadIdx.x;
  float inv_n = 1.0f / (float)nrows;
  float mu = stats[t] * inv_n;
  float var = stats[DIM + t] * inv_n - mu * mu;
  float rs = rsqrtf(var + 1e-5f);
  float g = flexload(gamma, t, f) * rs;
  float b = flexload(beta, t, f) - mu * g;
  for (int r = blockIdx.x; r < nrows; r += gridDim.x) {
    size_t idx = (size_t)r * DIM + t;
    float y = g * bf2f(x[idx]) + b;
    y = y > 0.f ? y : expm1f(y);
    x[idx] = f2bf(y);
  }
}

// ---------------- final linear: flex in/out ----------------

__global__ __launch_bounds__(256) void k_final(const void* __restrict__ x,
                                               const void* __restrict__ W,
                                               const void* __restrict__ bias,
                                               void* __restrict__ out, int nrows,
                                               const int* __restrict__ dflag) {
  __shared__ u16 xs[64 * DIM];
  __shared__ u16 wl[DIM * NCLS];
  int f = dflag[0];
  int t = threadIdx.x;
  int rowBase = blockIdx.x * 64;
  for (int i = t; i < 64 * DIM; i += 256) {
    int r = rowBase + (i >> 8);
    if (r >= nrows) r = nrows - 1;
    xs[i] = f2bf(flexload(x, (size_t)r * DIM + (i & 255), f));
  }
  for (int i = t; i < DIM * NCLS; i += 256) wl[i] = f2bf(flexload(W, i, f));
  __syncthreads();
  for (int o = t; o < 64 * NCLS; o += 256) {
    int r = o / NCLS;
    int c = o - r * NCLS;
    float acc = 0.f;
    const u16* xr = &xs[r * DIM];
#pragma unroll 8
    for (int k = 0; k < DIM; ++k) acc += bf2f(xr[k]) * bf2f(wl[k * NCLS + c]);
    int grow = rowBase + r;
    if (grow < nrows)
      flexstore(out, (size_t)N_NODES * DIM + (size_t)grow * NCLS + c, f,
                acc + flexload(bias, c, f));
  }
}

// ---------------- launch ----------------

extern "C" void kernel_launch(void* const* d_in, const int* in_sizes, int n_in,
                              void* d_out, int out_size, void* d_ws, size_t ws_size,
                              hipStream_t stream) {
  // expected input layout
  static const int EXP[15] = {51200000, 300000, 300000, 262144, 256, 65536, 256,
                              65536, 256, 65536, 256, 256, 256, 10240, 40};
  bool ok_sizes = (n_in == 15);
  if (ok_sizes)
    for (int i = 0; i < 15; ++i)
      if (in_sizes[i] != EXP[i]) ok_sizes = false;

  char* w = (char*)d_ws;
  size_t o = 0;
  auto take = [&](size_t bytes) {
    size_t r = o;
    o += (bytes + 255) & ~(size_t)255;
    return r;
  };
  size_t o_degf = take(N_NODES * 4);
  size_t o_degi = take(N_NODES * 4);
  size_t o_stat = take(1024 * 4);
  size_t zero_bytes = o;  // degf+degi+stats zeroed each call
  size_t o_flag = take(256);
  size_t o_ns = take(N_NODES * 4);
  size_t o_nd = take(N_NODES * 4);
  size_t o_rs = take((N_NODES + 1) * 4);
  size_t o_cur = take(N_NODES * 4);
  size_t o_csr = take(N_EDGES * 4);
  size_t o_wfc = take((size_t)FEAT * DIM * 2);
  size_t o_w1 = take(DIM * DIM * 2);
  size_t o_w2 = take(DIM * DIM * 2);
  size_t o_w3 = take(DIM * DIM * 2);
  size_t o_xa = take((size_t)N_NODES * DIM * 2);
  size_t required = o;

  // ---- diagnostic fallbacks (self-identifying absmax signatures) ----
  if (!ok_sizes || ws_size < required) {
    int* dflag0 = (int*)d_ws;  // assume ws_size >= 4KB for diagnostics
    float val = ok_sizes ? 1.0f : 2.0f;  // 1.0: ws too small; 2.0: size mismatch
    if (n_in > 0 && in_sizes[0] >= 2048)
      k_sniff<<<1, 256, 0, stream>>>((const u16*)d_in[0], dflag0);
    else
      k_setflag<<<1, 1, 0, stream>>>(dflag0, 0);
    k_filldiag<<<(out_size + 255) / 256, 256, 0, stream>>>(d_out, out_size, val, dflag0);
    return;
  }

  const void* feat = d_in[0];
  const int* src = (const int*)d_in[1];
  const int* dst = (const int*)d_in[2];
  const void* W_fc = d_in[3];
  const void* b_fc = d_in[4];
  const void* W1 = d_in[5];
  const void* b1 = d_in[6];
  const void* W2 = d_in[7];
  const void* b2 = d_in[8];
  const void* W3 = d_in[9];
  const void* b3 = d_in[10];
  const void* gamma = d_in[11];
  const void* beta = d_in[12];
  const void* W_lin = d_in[13];
  const void* b_lin = d_in[14];

  float* degf = (float*)(w + o_degf);
  int* degi = (int*)(w + o_degi);
  float* stats = (float*)(w + o_stat);
  int* dflag = (int*)(w + o_flag);
  float* norm_s = (float*)(w + o_ns);
  float* norm_d = (float*)(w + o_nd);
  int* row_start = (int*)(w + o_rs);
  int* cursor = (int*)(w + o_cur);
  int* csr_src = (int*)(w + o_csr);
  u16* WtFc = (u16*)(w + o_wfc);
  u16* Wt1 = (u16*)(w + o_w1);
  u16* Wt2 = (u16*)(w + o_w2);
  u16* Wt3 = (u16*)(w + o_w3);
  u16* xA = (u16*)(w + o_xa);

  // ping buffer lives in the d_out x-region (always used as internal bf16 u16s
  // for layers 1/2; layer-3 GEMM rewrites it in the output's real dtype)
  u16* ping = (u16*)d_out;

  k_sniff<<<1, 256, 0, stream>>>((const u16*)feat, dflag);

  int zero_words = (int)(zero_bytes / 4);
  k_zero<<<(zero_words + 255) / 256, 256, 0, stream>>>((unsigned*)(w + 0), zero_words);
  k_deg<<<(N_EDGES + 255) / 256, 256, 0, stream>>>(src, dst, degf, degi, N_EDGES);
  k_norm<<<(N_NODES + 255) / 256, 256, 0, stream>>>(degf, degi, norm_s, norm_d, N_NODES);
  k_scan<<<1, 1024, 0, stream>>>(degi, row_start, cursor, N_NODES);
  k_scatter<<<(N_EDGES + 255) / 256, 256, 0, stream>>>(src, dst, cursor, csr_src, N_EDGES);
  k_transpose<<<((FEAT * DIM) + 255) / 256, 256, 0, stream>>>(W_fc, WtFc, FEAT, DIM, dflag);
  k_transpose<<<((DIM * DIM) + 255) / 256, 256, 0, stream>>>(W1, Wt1, DIM, DIM, dflag);
  k_transpose<<<((DIM * DIM) + 255) / 256, 256, 0, stream>>>(W2, Wt2, DIM, DIM, dflag);
  k_transpose<<<((DIM * DIM) + 255) / 256, 256, 0, stream>>>(W3, Wt3, DIM, DIM, dflag);

  dim3 gg((N_NODES + 127) / 128, DIM / 128);

  // x0 = feat @ W_fc + b_fc  -> ping (internal bf16); feat load is flex
  k_gemm<<<gg, 256, 0, stream>>>(feat, WtFc, b_fc, ping, N_NODES, FEAT, DIM, 1, 0, dflag);

  // layer 1
  k_spmm<<<(N_NODES + 3) / 4, 256, 0, stream>>>(ping, xA, row_start, csr_src, norm_s, norm_d, N_NODES);
  k_gemm<<<gg, 256, 0, stream>>>(xA, Wt1, b1, ping, N_NODES, DIM, DIM, 0, 0, dflag);
  k_bnstats<<<512, 256, 0, stream>>>(ping, stats, N_NODES);
  k_bnapply<<<512, 256, 0, stream>>>(ping, stats, gamma, beta, N_NODES, dflag);

  // layer 2
  k_spmm<<<(N_NODES + 3) / 4, 256, 0, stream>>>(ping, xA, row_start, csr_src, norm_s, norm_d, N_NODES);
  k_gemm<<<gg, 256, 0, stream>>>(xA, Wt2, b2, ping, N_NODES, DIM, DIM, 0, 0, dflag);
  k_bnstats<<<512, 256, 0, stream>>>(ping, stats + 512, N_NODES);
  k_bnapply<<<512, 256, 0, stream>>>(ping, stats + 512, gamma, beta, N_NODES, dflag);

  // layer 3 -> output x written in the output's real dtype (flex C)
  k_spmm<<<(N_NODES + 3) / 4, 256, 0, stream>>>(ping, xA, row_start, csr_src, norm_s, norm_d, N_NODES);
  k_gemm<<<gg, 256, 0, stream>>>(xA, Wt3, b3, d_out, N_NODES, DIM, DIM, 0, 1, dflag);

  // logits (flex read of x from d_out, flex write of logits)
  k_final<<<(N_NODES + 63) / 64, 256, 0, stream>>>(d_out, W_lin, b_lin, d_out, N_NODES, dflag);
}

// Round 4
// 1010.004 us; speedup vs baseline: 1.0317x; 1.0317x over previous
//
#include <hip/hip_runtime.h>

#define N_NODES 50000
#define N_EDGES 300000
#define DIM 256
#define FEAT 1024
#define NCLS 40

typedef unsigned short u16;
typedef __attribute__((ext_vector_type(8))) short short8;
typedef __attribute__((ext_vector_type(4))) float float4v;

__device__ __forceinline__ float bf2f(u16 u) {
  union { float f; unsigned v; } x; x.v = ((unsigned)u) << 16; return x.f;
}
__device__ __forceinline__ u16 f2bf(float f) {
  union { float f; unsigned v; } x; x.f = f;
  unsigned r = 0x7fffu + ((x.v >> 16) & 1u);
  return (u16)((x.v + r) >> 16);
}
__device__ __forceinline__ float flexload(const void* p, size_t i, int f32) {
  return f32 ? ((const float*)p)[i] : bf2f(((const u16*)p)[i]);
}
__device__ __forceinline__ void flexstore(void* p, size_t i, int f32, float v) {
  if (f32) ((float*)p)[i] = v;
  else ((u16*)p)[i] = f2bf(v);
}
__device__ __forceinline__ void async16(const u16* g, u16* l) {
  __builtin_amdgcn_global_load_lds(
      (__attribute__((address_space(1))) void*)g,
      (__attribute__((address_space(3))) void*)l, 16, 0, 0);
}

// ---------------- dtype sniff ----------------
__global__ __launch_bounds__(256) void k_sniff(const u16* __restrict__ feat,
                                               int* __restrict__ dflag) {
  __shared__ int cnt[256];
  int t = threadIdx.x;
  int ok = 0;
  for (int j = 0; j < 4; ++j) {
    float v = bf2f(feat[(size_t)(t * 4 + j) * 2]);
    float a = fabsf(v);
    if (a < 64.0f && a > 1e-5f) ok++;
  }
  cnt[t] = ok;
  __syncthreads();
  for (int off = 128; off > 0; off >>= 1) {
    if (t < off) cnt[t] += cnt[t + off];
    __syncthreads();
  }
  if (t == 0) dflag[0] = (cnt[0] < 700) ? 1 : 0;
}

__global__ void k_setflag(int* dflag, int v) { dflag[0] = v; }

__global__ void k_filldiag(void* out, int n, float val, const int* __restrict__ dflag) {
  int i = blockIdx.x * blockDim.x + threadIdx.x;
  if (i < n) flexstore(out, i, dflag[0], val);
}

// ---------------- feat cast fp32 -> bf16 (no-op if already bf16) ----------------
__global__ __launch_bounds__(256) void k_cast(const void* __restrict__ feat,
                                              u16* __restrict__ xf,
                                              const int* __restrict__ dflag) {
  if (dflag[0] == 0) return;
  size_t i = ((size_t)blockIdx.x * 256 + threadIdx.x) * 8;
  const float* f = (const float*)feat;
  float4 a = *(const float4*)&f[i];
  float4 b = *(const float4*)&f[i + 4];
  uint4 o;
  o.x = (unsigned)f2bf(a.x) | ((unsigned)f2bf(a.y) << 16);
  o.y = (unsigned)f2bf(a.z) | ((unsigned)f2bf(a.w) << 16);
  o.z = (unsigned)f2bf(b.x) | ((unsigned)f2bf(b.y) << 16);
  o.w = (unsigned)f2bf(b.z) | ((unsigned)f2bf(b.w) << 16);
  *(uint4*)&xf[i] = o;
}

// ---------------- graph prep ----------------

__global__ void k_zero(unsigned* p, int n) {
  int i = blockIdx.x * blockDim.x + threadIdx.x;
  if (i < n) p[i] = 0u;
}

__global__ void k_deg(const int* __restrict__ src, const int* __restrict__ dst,
                      float* __restrict__ degf, int* __restrict__ degi, int e) {
  int i = blockIdx.x * blockDim.x + threadIdx.x;
  if (i < e) {
    atomicAdd(&degf[src[i]], 1.0f);
    atomicAdd(&degi[dst[i]], 1);
  }
}

__global__ void k_norm(const float* __restrict__ degf, const int* __restrict__ degi,
                       float* __restrict__ ns, float* __restrict__ nd, int n) {
  int i = blockIdx.x * blockDim.x + threadIdx.x;
  if (i < n) {
    ns[i] = rsqrtf(fmaxf(degf[i], 1.0f));
    nd[i] = rsqrtf(fmaxf((float)degi[i], 1.0f));
  }
}

__global__ __launch_bounds__(1024) void k_scan(const int* __restrict__ counts,
                                               int* __restrict__ row_start,
                                               int* __restrict__ cursor, int n) {
  __shared__ int wsum[16];
  __shared__ int carry_s;
  int t = threadIdx.x;
  int lane = t & 63, wv = t >> 6;
  if (t == 0) carry_s = 0;
  __syncthreads();
  for (int base = 0; base < n; base += 4096) {
    int i0 = base + t * 4;
    int v0 = 0, v1 = 0, v2 = 0, v3 = 0;
    if (i0 + 3 < n) {
      int4 c4 = *(const int4*)&counts[i0];
      v0 = c4.x; v1 = c4.y; v2 = c4.z; v3 = c4.w;
    } else {
      if (i0 < n) v0 = counts[i0];
      if (i0 + 1 < n) v1 = counts[i0 + 1];
      if (i0 + 2 < n) v2 = counts[i0 + 2];
      if (i0 + 3 < n) v3 = counts[i0 + 3];
    }
    int s = v0 + v1 + v2 + v3;
    int sc = s;
#pragma unroll
    for (int off = 1; off < 64; off <<= 1) {
      int u = __shfl_up(sc, off, 64);
      if (lane >= off) sc += u;
    }
    if (lane == 63) wsum[wv] = sc;
    __syncthreads();
    if (wv == 0) {
      int w_ = (lane < 16) ? wsum[lane] : 0;
#pragma unroll
      for (int off = 1; off < 16; off <<= 1) {
        int u = __shfl_up(w_, off, 64);
        if (lane >= off) w_ += u;
      }
      if (lane < 16) wsum[lane] = w_;
    }
    __syncthreads();
    int wbase = (wv == 0) ? 0 : wsum[wv - 1];
    int carry = carry_s;
    int excl = carry + wbase + (sc - s);
    if (i0 < n)     { int p = excl;                row_start[i0] = p;     cursor[i0] = p; }
    if (i0 + 1 < n) { int p = excl + v0;           row_start[i0 + 1] = p; cursor[i0 + 1] = p; }
    if (i0 + 2 < n) { int p = excl + v0 + v1;      row_start[i0 + 2] = p; cursor[i0 + 2] = p; }
    if (i0 + 3 < n) { int p = excl + v0 + v1 + v2; row_start[i0 + 3] = p; cursor[i0 + 3] = p; }
    __syncthreads();
    if (t == 1023) carry_s = carry + wbase + sc;
    __syncthreads();
  }
  if (t == 0) row_start[n] = carry_s;
}

__global__ void k_scatter(const int* __restrict__ src, const int* __restrict__ dst,
                          int* __restrict__ cursor, int* __restrict__ csr_src, int e) {
  int i = blockIdx.x * blockDim.x + threadIdx.x;
  if (i < e) {
    int pos = atomicAdd(&cursor[dst[i]], 1);
    csr_src[pos] = src[i];
  }
}

__global__ void k_transpose(const void* __restrict__ w, u16* __restrict__ wt,
                            int K, int Ncols, const int* __restrict__ dflag) {
  int f = dflag[0];
  int i = blockIdx.x * blockDim.x + threadIdx.x;
  if (i < K * Ncols) {
    int k = i / Ncols;
    int c = i - k * Ncols;
    wt[c * K + k] = f2bf(flexload(w, i, f));
  }
}

// ---------------- async MFMA GEMM (bf16 A), optional fused BN column stats ----------------
// C[M,Nc] = A[M,K] @ B + bias; Bt is [Nc,K] bf16. 128x128 tile, 4 waves, BK=64.
// A-pointer selected in-kernel: f ? A1 : A0 (both bf16 views).

__global__ __launch_bounds__(256) void k_gemm_a(
    const u16* __restrict__ A0, const u16* __restrict__ A1,
    const u16* __restrict__ Bt, const void* __restrict__ bias,
    void* __restrict__ Cmat, int M, int K, int Nc, int c_flex,
    float* __restrict__ stats, const int* __restrict__ dflag) {
  __shared__ __align__(16) u16 As[64 * 128];  // [kq(8)][m(128)][8]
  __shared__ __align__(16) u16 Bs[64 * 128];  // [kq(8)][n(128)][8]

  const int f = dflag[0];
  const u16* A = f ? A1 : A0;
  const int cf = c_flex & f;

  const int tid = threadIdx.x;
  const int lane = tid & 63;
  const int wv = tid >> 6;
  const int wm = (wv >> 1) * 64;
  const int wn = (wv & 1) * 64;
  const int quad = lane >> 4;
  const int l15 = lane & 15;
  const int rowBase = blockIdx.x * 128;
  const int colBase = blockIdx.y * 128;

  float4v acc[4][4];
#pragma unroll
  for (int a = 0; a < 4; ++a)
#pragma unroll
    for (int b = 0; b < 4; ++b) {
      acc[a][b][0] = 0.f; acc[a][b][1] = 0.f; acc[a][b][2] = 0.f; acc[a][b][3] = 0.f;
    }

  for (int k0 = 0; k0 < K; k0 += 64) {
    __syncthreads();
#pragma unroll
    for (int r = 0; r < 4; ++r) {
      int j = r * 256 + tid;
      int kq = j >> 7;
      int ml = j & 127;
      int grow = rowBase + ml;
      if (grow >= M) grow = M - 1;
      async16(&A[(size_t)grow * K + k0 + kq * 8], &As[j * 8]);
      async16(&Bt[(size_t)(colBase + ml) * K + k0 + kq * 8], &Bs[j * 8]);
    }
    __syncthreads();
#pragma unroll
    for (int ks = 0; ks < 2; ++ks) {
      short8 afr[4], bfr[4];
#pragma unroll
      for (int t = 0; t < 4; ++t) {
        int kq = ks * 4 + quad;
        afr[t] = *(const short8*)&As[(kq * 128 + wm + t * 16 + l15) * 8];
        bfr[t] = *(const short8*)&Bs[(kq * 128 + wn + t * 16 + l15) * 8];
      }
#pragma unroll
      for (int mt = 0; mt < 4; ++mt)
#pragma unroll
        for (int nt = 0; nt < 4; ++nt)
          acc[mt][nt] = __builtin_amdgcn_mfma_f32_16x16x32_bf16(
              afr[mt], bfr[nt], acc[mt][nt], 0, 0, 0);
    }
  }

#pragma unroll
  for (int nt = 0; nt < 4; ++nt) {
    int col = colBase + wn + nt * 16 + l15;
    float bv = flexload(bias, col, f);
    float s = 0.f, s2 = 0.f;
#pragma unroll
    for (int mt = 0; mt < 4; ++mt) {
#pragma unroll
      for (int r = 0; r < 4; ++r) {
        int row = rowBase + wm + mt * 16 + quad * 4 + r;
        if (row < M) {
          float v = acc[mt][nt][r] + bv;
          if (cf) ((float*)Cmat)[(size_t)row * Nc + col] = v;
          else ((u16*)Cmat)[(size_t)row * Nc + col] = f2bf(v);
          s += v;
          s2 += v * v;
        }
      }
    }
    if (stats) {
      s += __shfl_down(s, 32, 64);
      s += __shfl_down(s, 16, 64);
      s2 += __shfl_down(s2, 32, 64);
      s2 += __shfl_down(s2, 16, 64);
      if (quad == 0) {
        atomicAdd(&stats[col], s);
        atomicAdd(&stats[DIM + col], s2);
      }
    }
  }
}

// ---------------- flex-A GEMM (round-3 fallback; used for fc when ws can't fit cast) ----
__global__ __launch_bounds__(256) void k_gemm_flex(
    const void* __restrict__ A, const u16* __restrict__ Bt,
    const void* __restrict__ bias, void* __restrict__ Cmat,
    int M, int K, int Nc, int a_flex, int c_flex,
    const int* __restrict__ dflag) {
  __shared__ __align__(16) u16 As[64 * 128];
  __shared__ __align__(16) u16 Bs[64 * 128];
  const int f = dflag[0];
  const int af = a_flex & f;
  const int cf = c_flex & f;
  const int tid = threadIdx.x;
  const int lane = tid & 63;
  const int wv = tid >> 6;
  const int wm = (wv >> 1) * 64;
  const int wn = (wv & 1) * 64;
  const int quad = lane >> 4;
  const int l15 = lane & 15;
  const int rowBase = blockIdx.x * 128;
  const int colBase = blockIdx.y * 128;
  float4v acc[4][4];
#pragma unroll
  for (int a = 0; a < 4; ++a)
#pragma unroll
    for (int b = 0; b < 4; ++b) {
      acc[a][b][0] = 0.f; acc[a][b][1] = 0.f; acc[a][b][2] = 0.f; acc[a][b][3] = 0.f;
    }
  for (int k0 = 0; k0 < K; k0 += 64) {
    __syncthreads();
#pragma unroll
    for (int r = 0; r < 4; ++r) {
      int j = r * 256 + tid;
      int kq = j >> 7;
      int ml = j & 127;
      int grow = rowBase + ml;
      if (grow >= M) grow = M - 1;
      size_t abase = (size_t)grow * K + k0 + kq * 8;
      if (af) {
        const float* Af = (const float*)A;
        float4 lo = *(const float4*)&Af[abase];
        float4 hi = *(const float4*)&Af[abase + 4];
        u16* d = &As[j * 8];
        d[0] = f2bf(lo.x); d[1] = f2bf(lo.y); d[2] = f2bf(lo.z); d[3] = f2bf(lo.w);
        d[4] = f2bf(hi.x); d[5] = f2bf(hi.y); d[6] = f2bf(hi.z); d[7] = f2bf(hi.w);
      } else {
        const u16* Au = (const u16*)A;
        *(uint4*)&As[j * 8] = *(const uint4*)&Au[abase];
      }
      *(uint4*)&Bs[j * 8] = *(const uint4*)&Bt[(size_t)(colBase + ml) * K + k0 + kq * 8];
    }
    __syncthreads();
#pragma unroll
    for (int ks = 0; ks < 2; ++ks) {
      short8 afr[4], bfr[4];
#pragma unroll
      for (int t = 0; t < 4; ++t) {
        int kq = ks * 4 + quad;
        afr[t] = *(const short8*)&As[(kq * 128 + wm + t * 16 + l15) * 8];
        bfr[t] = *(const short8*)&Bs[(kq * 128 + wn + t * 16 + l15) * 8];
      }
#pragma unroll
      for (int mt = 0; mt < 4; ++mt)
#pragma unroll
        for (int nt = 0; nt < 4; ++nt)
          acc[mt][nt] = __builtin_amdgcn_mfma_f32_16x16x32_bf16(
              afr[mt], bfr[nt], acc[mt][nt], 0, 0, 0);
    }
  }
#pragma unroll
  for (int nt = 0; nt < 4; ++nt) {
    int col = colBase + wn + nt * 16 + l15;
    float bv = flexload(bias, col, f);
#pragma unroll
    for (int mt = 0; mt < 4; ++mt) {
#pragma unroll
      for (int r = 0; r < 4; ++r) {
        int row = rowBase + wm + mt * 16 + quad * 4 + r;
        if (row < M) {
          float v = acc[mt][nt][r] + bv;
          if (cf) ((float*)Cmat)[(size_t)row * Nc + col] = v;
          else ((u16*)Cmat)[(size_t)row * Nc + col] = f2bf(v);
        }
      }
    }
  }
}

// ---------------- SpMM ----------------

__global__ __launch_bounds__(256) void k_spmm(
    const u16* __restrict__ x, u16* __restrict__ y,
    const int* __restrict__ row_start, const int* __restrict__ csr_src,
    const float* __restrict__ ns, const float* __restrict__ nd, int n) {
  int wid = (blockIdx.x * blockDim.x + threadIdx.x) >> 6;
  int lane = threadIdx.x & 63;
  if (wid >= n) return;
  int e0 = row_start[wid];
  int e1 = row_start[wid + 1];
  int c = lane * 4;
  float a0 = 0.f, a1 = 0.f, a2 = 0.f, a3 = 0.f;
  for (int e = e0; e < e1; ++e) {
    int s = csr_src[e];
    float w = ns[s];
    uint2 v = *(const uint2*)&x[(size_t)s * DIM + c];
    a0 += w * bf2f((u16)(v.x & 0xffffu));
    a1 += w * bf2f((u16)(v.x >> 16));
    a2 += w * bf2f((u16)(v.y & 0xffffu));
    a3 += w * bf2f((u16)(v.y >> 16));
  }
  float wd = nd[wid];
  uint2 o;
  o.x = (unsigned)f2bf(a0 * wd) | ((unsigned)f2bf(a1 * wd) << 16);
  o.y = (unsigned)f2bf(a2 * wd) | ((unsigned)f2bf(a3 * wd) << 16);
  *(uint2*)&y[(size_t)wid * DIM + c] = o;
}

// ---------------- BN finalize + apply ----------------

__global__ __launch_bounds__(256) void k_bnfin(const float* __restrict__ stats,
                                               const void* __restrict__ gamma,
                                               const void* __restrict__ beta,
                                               float* __restrict__ gb, int nrows,
                                               const int* __restrict__ dflag) {
  int f = dflag[0];
  int t = threadIdx.x;
  float inv_n = 1.0f / (float)nrows;
  float mu = stats[t] * inv_n;
  float var = stats[DIM + t] * inv_n - mu * mu;
  float rs = rsqrtf(var + 1e-5f);
  float g = flexload(gamma, t, f) * rs;
  float b = flexload(beta, t, f) - mu * g;
  gb[t] = g;
  gb[DIM + t] = b;
}

__global__ __launch_bounds__(256) void k_bnapply(u16* __restrict__ x,
                                                 const float* __restrict__ gb, int nrows) {
  int t = threadIdx.x;
  float g = gb[t];
  float b = gb[DIM + t];
  for (int r = blockIdx.x; r < nrows; r += gridDim.x) {
    size_t idx = (size_t)r * DIM + t;
    float y = g * bf2f(x[idx]) + b;
    y = y > 0.f ? y : expm1f(y);
    x[idx] = f2bf(y);
  }
}

// ---------------- final linear ----------------

__global__ __launch_bounds__(256) void k_final(const void* __restrict__ x,
                                               const void* __restrict__ W,
                                               const void* __restrict__ bias,
                                               void* __restrict__ out, int nrows,
                                               const int* __restrict__ dflag) {
  __shared__ u16 xs[64 * DIM];
  __shared__ u16 wl[DIM * NCLS];
  int f = dflag[0];
  int t = threadIdx.x;
  int rowBase = blockIdx.x * 64;
  for (int i = t; i < 64 * DIM; i += 256) {
    int r = rowBase + (i >> 8);
    if (r >= nrows) r = nrows - 1;
    xs[i] = f2bf(flexload(x, (size_t)r * DIM + (i & 255), f));
  }
  for (int i = t; i < DIM * NCLS; i += 256) wl[i] = f2bf(flexload(W, i, f));
  __syncthreads();
  for (int o = t; o < 64 * NCLS; o += 256) {
    int r = o / NCLS;
    int c = o - r * NCLS;
    float acc = 0.f;
    const u16* xr = &xs[r * DIM];
#pragma unroll 8
    for (int k = 0; k < DIM; ++k) acc += bf2f(xr[k]) * bf2f(wl[k * NCLS + c]);
    int grow = rowBase + r;
    if (grow < nrows)
      flexstore(out, (size_t)N_NODES * DIM + (size_t)grow * NCLS + c, f,
                acc + flexload(bias, c, f));
  }
}

// ---------------- launch ----------------

extern "C" void kernel_launch(void* const* d_in, const int* in_sizes, int n_in,
                              void* d_out, int out_size, void* d_ws, size_t ws_size,
                              hipStream_t stream) {
  static const int EXP[15] = {51200000, 300000, 300000, 262144, 256, 65536, 256,
                              65536, 256, 65536, 256, 256, 256, 10240, 40};
  bool ok_sizes = (n_in == 15);
  if (ok_sizes)
    for (int i = 0; i < 15; ++i)
      if (in_sizes[i] != EXP[i]) ok_sizes = false;

  char* w = (char*)d_ws;
  size_t o = 0;
  auto take = [&](size_t bytes) {
    size_t r = o;
    o += (bytes + 255) & ~(size_t)255;
    return r;
  };
  size_t o_degf = take(N_NODES * 4);
  size_t o_degi = take(N_NODES * 4);
  size_t o_stat = take(1024 * 4);
  size_t zero_bytes = o;  // degf+degi+stats zeroed each call
  size_t o_flag = take(256);
  size_t o_gb = take(512 * 4);
  size_t o_ns = take(N_NODES * 4);
  size_t o_nd = take(N_NODES * 4);
  size_t o_rs = take((N_NODES + 1) * 4);
  size_t o_cur = take(N_NODES * 4);
  size_t o_csr = take(N_EDGES * 4);
  size_t o_wfc = take((size_t)FEAT * DIM * 2);
  size_t o_w1 = take(DIM * DIM * 2);
  size_t o_w2 = take(DIM * DIM * 2);
  size_t o_w3 = take(DIM * DIM * 2);
  size_t o_xa = take((size_t)N_NODES * DIM * 2);
  size_t required = o;
  size_t o_xf = take((size_t)N_NODES * FEAT * 2);  // 102.4 MB cast buffer (optional)
  size_t required_xf = o;
  bool have_xf = ws_size >= required_xf;

  if (!ok_sizes || ws_size < required) {
    int* dflag0 = (int*)d_ws;
    float val = ok_sizes ? 1.0f : 2.0f;
    if (n_in > 0 && in_sizes[0] >= 2048)
      k_sniff<<<1, 256, 0, stream>>>((const u16*)d_in[0], dflag0);
    else
      k_setflag<<<1, 1, 0, stream>>>(dflag0, 0);
    k_filldiag<<<(out_size + 255) / 256, 256, 0, stream>>>(d_out, out_size, val, dflag0);
    return;
  }

  const void* feat = d_in[0];
  const int* src = (const int*)d_in[1];
  const int* dst = (const int*)d_in[2];
  const void* W_fc = d_in[3];
  const void* b_fc = d_in[4];
  const void* W1 = d_in[5];
  const void* b1 = d_in[6];
  const void* W2 = d_in[7];
  const void* b2 = d_in[8];
  const void* W3 = d_in[9];
  const void* b3 = d_in[10];
  const void* gamma = d_in[11];
  const void* beta = d_in[12];
  const void* W_lin = d_in[13];
  const void* b_lin = d_in[14];

  float* degf = (float*)(w + o_degf);
  int* degi = (int*)(w + o_degi);
  float* stats = (float*)(w + o_stat);
  int* dflag = (int*)(w + o_flag);
  float* gb = (float*)(w + o_gb);
  float* norm_s = (float*)(w + o_ns);
  float* norm_d = (float*)(w + o_nd);
  int* row_start = (int*)(w + o_rs);
  int* cursor = (int*)(w + o_cur);
  int* csr_src = (int*)(w + o_csr);
  u16* WtFc = (u16*)(w + o_wfc);
  u16* Wt1 = (u16*)(w + o_w1);
  u16* Wt2 = (u16*)(w + o_w2);
  u16* Wt3 = (u16*)(w + o_w3);
  u16* xA = (u16*)(w + o_xa);
  u16* xF = (u16*)(w + o_xf);

  u16* ping = (u16*)d_out;  // d_out x-region doubles as internal bf16 ping buffer

  k_sniff<<<1, 256, 0, stream>>>((const u16*)feat, dflag);

  int zero_words = (int)(zero_bytes / 4);
  k_zero<<<(zero_words + 255) / 256, 256, 0, stream>>>((unsigned*)(w + 0), zero_words);
  k_deg<<<(N_EDGES + 255) / 256, 256, 0, stream>>>(src, dst, degf, degi, N_EDGES);
  k_norm<<<(N_NODES + 255) / 256, 256, 0, stream>>>(degf, degi, norm_s, norm_d, N_NODES);
  k_scan<<<1, 1024, 0, stream>>>(degi, row_start, cursor, N_NODES);
  k_scatter<<<(N_EDGES + 255) / 256, 256, 0, stream>>>(src, dst, cursor, csr_src, N_EDGES);
  k_transpose<<<((FEAT * DIM) + 255) / 256, 256, 0, stream>>>(W_fc, WtFc, FEAT, DIM, dflag);
  k_transpose<<<((DIM * DIM) + 255) / 256, 256, 0, stream>>>(W1, Wt1, DIM, DIM, dflag);
  k_transpose<<<((DIM * DIM) + 255) / 256, 256, 0, stream>>>(W2, Wt2, DIM, DIM, dflag);
  k_transpose<<<((DIM * DIM) + 255) / 256, 256, 0, stream>>>(W3, Wt3, DIM, DIM, dflag);

  dim3 gg((N_NODES + 127) / 128, DIM / 128);

  // x0 = feat @ W_fc + b_fc -> ping (internal bf16)
  if (have_xf) {
    k_cast<<<(N_NODES * FEAT) / (256 * 8), 256, 0, stream>>>(feat, xF, dflag);
    k_gemm_a<<<gg, 256, 0, stream>>>((const u16*)feat, xF, WtFc, b_fc, ping,
                                     N_NODES, FEAT, DIM, 0, (float*)nullptr, dflag);
  } else {
    k_gemm_flex<<<gg, 256, 0, stream>>>(feat, WtFc, b_fc, ping,
                                        N_NODES, FEAT, DIM, 1, 0, dflag);
  }

  // layer 1 (fused BN stats in GEMM epilogue)
  k_spmm<<<(N_NODES + 3) / 4, 256, 0, stream>>>(ping, xA, row_start, csr_src, norm_s, norm_d, N_NODES);
  k_gemm_a<<<gg, 256, 0, stream>>>(xA, xA, Wt1, b1, ping, N_NODES, DIM, DIM, 0, stats, dflag);
  k_bnfin<<<1, 256, 0, stream>>>(stats, gamma, beta, gb, N_NODES, dflag);
  k_bnapply<<<512, 256, 0, stream>>>(ping, gb, N_NODES);

  // layer 2
  k_spmm<<<(N_NODES + 3) / 4, 256, 0, stream>>>(ping, xA, row_start, csr_src, norm_s, norm_d, N_NODES);
  k_gemm_a<<<gg, 256, 0, stream>>>(xA, xA, Wt2, b2, ping, N_NODES, DIM, DIM, 0, stats + 512, dflag);
  k_bnfin<<<1, 256, 0, stream>>>(stats + 512, gamma, beta, gb, N_NODES, dflag);
  k_bnapply<<<512, 256, 0, stream>>>(ping, gb, N_NODES);

  // layer 3 -> output x (real output dtype)
  k_spmm<<<(N_NODES + 3) / 4, 256, 0, stream>>>(ping, xA, row_start, csr_src, norm_s, norm_d, N_NODES);
  k_gemm_a<<<gg, 256, 0, stream>>>(xA, xA, Wt3, b3, d_out, N_NODES, DIM, DIM, 1, (float*)nullptr, dflag);

  // logits
  k_final<<<(N_NODES + 63) / 64, 256, 0, stream>>>(d_out, W_lin, b_lin, d_out, N_NODES, dflag);
}

// Round 5
// 933.027 us; speedup vs baseline: 1.1169x; 1.0825x over previous
//
#include <hip/hip_runtime.h>
#include <hip/hip_bf16.h>

#define N_NODES 50000
#define N_EDGES 300000
#define DIM 256
#define FEAT 1024
#define NCLS 40
#define WPAD 264  // 256 + 8 u16 pad: LDS row stride 528B -> 2-way (free) banks

typedef unsigned short u16;
typedef __attribute__((ext_vector_type(8))) short short8;
typedef __attribute__((ext_vector_type(4))) float float4v;

__device__ __forceinline__ float bf2f(u16 u) {
  union { float f; unsigned v; } x; x.v = ((unsigned)u) << 16; return x.f;
}
__device__ __forceinline__ u16 f2bf(float f) {
  union { float f; unsigned v; } x; x.f = f;
  unsigned r = 0x7fffu + ((x.v >> 16) & 1u);
  return (u16)((x.v + r) >> 16);
}
__device__ __forceinline__ unsigned pk2(float a, float b) {
  union { __hip_bfloat162 h; unsigned u; } cv;
  cv.h = __float22bfloat162_rn(make_float2(a, b));
  return cv.u;
}
__device__ __forceinline__ float flexload(const void* p, size_t i, int f32) {
  return f32 ? ((const float*)p)[i] : bf2f(((const u16*)p)[i]);
}
__device__ __forceinline__ void flexstore(void* p, size_t i, int f32, float v) {
  if (f32) ((float*)p)[i] = v;
  else ((u16*)p)[i] = f2bf(v);
}
__device__ __forceinline__ void async16(const void* g, void* l) {
  __builtin_amdgcn_global_load_lds(
      (__attribute__((address_space(1))) void*)g,
      (__attribute__((address_space(3))) void*)l, 16, 0, 0);
}

// ---------------- dtype sniff ----------------
__global__ __launch_bounds__(256) void k_sniff(const u16* __restrict__ feat,
                                               int* __restrict__ dflag) {
  __shared__ int cnt[256];
  int t = threadIdx.x;
  int ok = 0;
  for (int j = 0; j < 4; ++j) {
    float v = bf2f(feat[(size_t)(t * 4 + j) * 2]);
    float a = fabsf(v);
    if (a < 64.0f && a > 1e-5f) ok++;
  }
  cnt[t] = ok;
  __syncthreads();
  for (int off = 128; off > 0; off >>= 1) {
    if (t < off) cnt[t] += cnt[t + off];
    __syncthreads();
  }
  if (t == 0) dflag[0] = (cnt[0] < 700) ? 1 : 0;
}

__global__ void k_setflag(int* dflag, int v) { dflag[0] = v; }

__global__ void k_filldiag(void* out, int n, float val, const int* __restrict__ dflag) {
  int i = blockIdx.x * blockDim.x + threadIdx.x;
  if (i < n) flexstore(out, i, dflag[0], val);
}

// ---------------- graph prep ----------------

__global__ void k_zero(unsigned* p, int n) {
  int i = blockIdx.x * blockDim.x + threadIdx.x;
  if (i < n) p[i] = 0u;
}

__global__ void k_deg(const int* __restrict__ src, const int* __restrict__ dst,
                      float* __restrict__ degf, int* __restrict__ degi, int e) {
  int i = blockIdx.x * blockDim.x + threadIdx.x;
  if (i < e) {
    atomicAdd(&degf[src[i]], 1.0f);
    atomicAdd(&degi[dst[i]], 1);
  }
}

__global__ void k_norm(const float* __restrict__ degf, const int* __restrict__ degi,
                       float* __restrict__ ns, float* __restrict__ nd, int n) {
  int i = blockIdx.x * blockDim.x + threadIdx.x;
  if (i < n) {
    ns[i] = rsqrtf(fmaxf(degf[i], 1.0f));
    nd[i] = rsqrtf(fmaxf((float)degi[i], 1.0f));
  }
}

__global__ __launch_bounds__(1024) void k_scan(const int* __restrict__ counts,
                                               int* __restrict__ row_start,
                                               int* __restrict__ cursor, int n) {
  __shared__ int wsum[16];
  __shared__ int carry_s;
  int t = threadIdx.x;
  int lane = t & 63, wv = t >> 6;
  if (t == 0) carry_s = 0;
  __syncthreads();
  for (int base = 0; base < n; base += 4096) {
    int i0 = base + t * 4;
    int v0 = 0, v1 = 0, v2 = 0, v3 = 0;
    if (i0 + 3 < n) {
      int4 c4 = *(const int4*)&counts[i0];
      v0 = c4.x; v1 = c4.y; v2 = c4.z; v3 = c4.w;
    } else {
      if (i0 < n) v0 = counts[i0];
      if (i0 + 1 < n) v1 = counts[i0 + 1];
      if (i0 + 2 < n) v2 = counts[i0 + 2];
      if (i0 + 3 < n) v3 = counts[i0 + 3];
    }
    int s = v0 + v1 + v2 + v3;
    int sc = s;
#pragma unroll
    for (int off = 1; off < 64; off <<= 1) {
      int u = __shfl_up(sc, off, 64);
      if (lane >= off) sc += u;
    }
    if (lane == 63) wsum[wv] = sc;
    __syncthreads();
    if (wv == 0) {
      int w_ = (lane < 16) ? wsum[lane] : 0;
#pragma unroll
      for (int off = 1; off < 16; off <<= 1) {
        int u = __shfl_up(w_, off, 64);
        if (lane >= off) w_ += u;
      }
      if (lane < 16) wsum[lane] = w_;
    }
    __syncthreads();
    int wbase = (wv == 0) ? 0 : wsum[wv - 1];
    int carry = carry_s;
    int excl = carry + wbase + (sc - s);
    if (i0 < n)     { int p = excl;                row_start[i0] = p;     cursor[i0] = p; }
    if (i0 + 1 < n) { int p = excl + v0;           row_start[i0 + 1] = p; cursor[i0 + 1] = p; }
    if (i0 + 2 < n) { int p = excl + v0 + v1;      row_start[i0 + 2] = p; cursor[i0 + 2] = p; }
    if (i0 + 3 < n) { int p = excl + v0 + v1 + v2; row_start[i0 + 3] = p; cursor[i0 + 3] = p; }
    __syncthreads();
    if (t == 1023) carry_s = carry + wbase + sc;
    __syncthreads();
  }
  if (t == 0) row_start[n] = carry_s;
}

__global__ void k_scatter(const int* __restrict__ src, const int* __restrict__ dst,
                          int* __restrict__ cursor, int* __restrict__ csr_src, int e) {
  int i = blockIdx.x * blockDim.x + threadIdx.x;
  if (i < e) {
    int pos = atomicAdd(&cursor[dst[i]], 1);
    csr_src[pos] = src[i];
  }
}

__global__ void k_transpose(const void* __restrict__ w, u16* __restrict__ wt,
                            int K, int Ncols, const int* __restrict__ dflag) {
  int f = dflag[0];
  int i = blockIdx.x * blockDim.x + threadIdx.x;
  if (i < K * Ncols) {
    int k = i / Ncols;
    int c = i - k * Ncols;
    wt[c * K + k] = f2bf(flexload(w, i, f));
  }
}

// ---------------- combined final weights: Wc = W3 @ W_lin (bf16, [48(pad)][256]) ----
__global__ __launch_bounds__(256) void k_combo(const void* __restrict__ W3,
                                               const void* __restrict__ Wlin,
                                               u16* __restrict__ Wct,
                                               const int* __restrict__ dflag) {
  int f = dflag[0];
  int c = blockIdx.x;   // 0..47
  int k = threadIdx.x;  // 0..255
  float acc = 0.f;
  if (c < NCLS)
    for (int n = 0; n < DIM; ++n)
      acc += flexload(W3, (size_t)k * DIM + n, f) * flexload(Wlin, (size_t)n * NCLS + c, f);
  Wct[c * WPAD + k] = f2bf(acc);
}

__global__ void k_combobias(const void* __restrict__ b3, const void* __restrict__ Wlin,
                            const void* __restrict__ blin, float* __restrict__ bcb,
                            const int* __restrict__ dflag) {
  int f = dflag[0];
  int c = threadIdx.x;
  if (c >= NCLS) return;
  float acc = flexload(blin, c, f);
  for (int n = 0; n < DIM; ++n)
    acc += flexload(b3, n, f) * flexload(Wlin, (size_t)n * NCLS + c, f);
  bcb[c] = acc;
}

// ---------------- fc GEMM: ping[M,256] = feat[M,1024] @ WtFc^T + b_fc ----------------
// Single 256-col tile (A read once). fp32 A staged raw via global_load_lds,
// packed to bf16 at fragment-read time (v_cvt_pk_bf16_f32). 64 KB LDS, 2 blk/CU.

__global__ __launch_bounds__(256) void k_gemm_fc(
    const void* __restrict__ A, const u16* __restrict__ Bt,
    const void* __restrict__ bias, u16* __restrict__ Cmat,
    int M, const int* __restrict__ dflag) {
  __shared__ __align__(16) u16 lds_[32768];        // 64 KB
  u16* Bs = lds_;                                  // 32 KB: [kq8][n256][8]
  u16* Asb = lds_ + 16384;                         // bf16 A: [kq8][m128][8]
  float* Asf = (float*)(lds_ + 16384);             // fp32 A: [kq8][m128][half2][4f]

  const int f = dflag[0];
  const int tid = threadIdx.x;
  const int lane = tid & 63;
  const int wv = tid >> 6;
  const int wm = (wv >> 1) * 64;
  const int wn = (wv & 1) * 128;
  const int quad = lane >> 4;
  const int l15 = lane & 15;
  const int rowBase = blockIdx.x * 128;

  float4v acc[4][8];
#pragma unroll
  for (int a = 0; a < 4; ++a)
#pragma unroll
    for (int b = 0; b < 8; ++b) {
      acc[a][b][0] = 0.f; acc[a][b][1] = 0.f; acc[a][b][2] = 0.f; acc[a][b][3] = 0.f;
    }

  for (int k0 = 0; k0 < FEAT; k0 += 64) {
    __syncthreads();
#pragma unroll
    for (int r = 0; r < 8; ++r) {  // B: 256 cols x 64 k = 2048 16B-chunks
      int j = r * 256 + tid;
      int kq = j >> 8, n = j & 255;
      async16(&Bt[(size_t)n * FEAT + k0 + kq * 8], &Bs[(size_t)j * 8]);
    }
    if (f) {
      const float* Af = (const float*)A;
#pragma unroll
      for (int r = 0; r < 8; ++r) {  // A fp32: 128 rows x 64 k x 4B = 2048 chunks
        int j = r * 256 + tid;
        int kq = j >> 8, m = (j & 255) >> 1, half = j & 1;
        int grow = rowBase + m;
        if (grow >= M) grow = M - 1;
        async16(&Af[(size_t)grow * FEAT + k0 + kq * 8 + half * 4], &Asf[(size_t)j * 4]);
      }
    } else {
      const u16* Au = (const u16*)A;
#pragma unroll
      for (int r = 0; r < 4; ++r) {  // A bf16: 1024 chunks
        int j = r * 256 + tid;
        int kq = j >> 7, m = j & 127;
        int grow = rowBase + m;
        if (grow >= M) grow = M - 1;
        async16(&Au[(size_t)grow * FEAT + k0 + kq * 8], &Asb[(size_t)j * 8]);
      }
    }
    __syncthreads();
#pragma unroll
    for (int ks = 0; ks < 2; ++ks) {
      int kq = ks * 4 + quad;
      short8 afr[4], bfr[8];
      if (f) {
#pragma unroll
        for (int t = 0; t < 4; ++t) {
          int row = wm + t * 16 + l15;
          float4 lo = *(const float4*)&Asf[(size_t)((kq * 128 + row) * 2 + 0) * 4];
          float4 hi = *(const float4*)&Asf[(size_t)((kq * 128 + row) * 2 + 1) * 4];
          union { short8 s; unsigned u[4]; } o;
          o.u[0] = pk2(lo.x, lo.y); o.u[1] = pk2(lo.z, lo.w);
          o.u[2] = pk2(hi.x, hi.y); o.u[3] = pk2(hi.z, hi.w);
          afr[t] = o.s;
        }
      } else {
#pragma unroll
        for (int t = 0; t < 4; ++t)
          afr[t] = *(const short8*)&Asb[(size_t)(kq * 128 + wm + t * 16 + l15) * 8];
      }
#pragma unroll
      for (int t = 0; t < 8; ++t)
        bfr[t] = *(const short8*)&Bs[(size_t)(kq * 256 + wn + t * 16 + l15) * 8];
#pragma unroll
      for (int mt = 0; mt < 4; ++mt)
#pragma unroll
        for (int nt = 0; nt < 8; ++nt)
          acc[mt][nt] = __builtin_amdgcn_mfma_f32_16x16x32_bf16(
              afr[mt], bfr[nt], acc[mt][nt], 0, 0, 0);
    }
  }

#pragma unroll
  for (int nt = 0; nt < 8; ++nt) {
    int col = wn + nt * 16 + l15;
    float bv = flexload(bias, col, f);
#pragma unroll
    for (int mt = 0; mt < 4; ++mt) {
#pragma unroll
      for (int r = 0; r < 4; ++r) {
        int row = rowBase + wm + mt * 16 + quad * 4 + r;
        if (row < M) Cmat[(size_t)row * DIM + col] = f2bf(acc[mt][nt][r] + bv);
      }
    }
  }
}

// ---------------- D-GEMM: async staging, optional fused BN column stats ----------------

__global__ __launch_bounds__(256) void k_gemm_a(
    const u16* __restrict__ A, const u16* __restrict__ Bt,
    const void* __restrict__ bias, void* __restrict__ Cmat,
    int M, int K, int Nc, int c_flex, float* __restrict__ stats,
    const int* __restrict__ dflag) {
  __shared__ __align__(16) u16 As[64 * 128];
  __shared__ __align__(16) u16 Bs[64 * 128];

  const int f = dflag[0];
  const int cf = c_flex & f;

  const int tid = threadIdx.x;
  const int lane = tid & 63;
  const int wv = tid >> 6;
  const int wm = (wv >> 1) * 64;
  const int wn = (wv & 1) * 64;
  const int quad = lane >> 4;
  const int l15 = lane & 15;
  const int rowBase = blockIdx.x * 128;
  const int colBase = blockIdx.y * 128;

  float4v acc[4][4];
#pragma unroll
  for (int a = 0; a < 4; ++a)
#pragma unroll
    for (int b = 0; b < 4; ++b) {
      acc[a][b][0] = 0.f; acc[a][b][1] = 0.f; acc[a][b][2] = 0.f; acc[a][b][3] = 0.f;
    }

  for (int k0 = 0; k0 < K; k0 += 64) {
    __syncthreads();
#pragma unroll
    for (int r = 0; r < 4; ++r) {
      int j = r * 256 + tid;
      int kq = j >> 7;
      int ml = j & 127;
      int grow = rowBase + ml;
      if (grow >= M) grow = M - 1;
      async16(&A[(size_t)grow * K + k0 + kq * 8], &As[(size_t)j * 8]);
      async16(&Bt[(size_t)(colBase + ml) * K + k0 + kq * 8], &Bs[(size_t)j * 8]);
    }
    __syncthreads();
#pragma unroll
    for (int ks = 0; ks < 2; ++ks) {
      short8 afr[4], bfr[4];
#pragma unroll
      for (int t = 0; t < 4; ++t) {
        int kq = ks * 4 + quad;
        afr[t] = *(const short8*)&As[(size_t)(kq * 128 + wm + t * 16 + l15) * 8];
        bfr[t] = *(const short8*)&Bs[(size_t)(kq * 128 + wn + t * 16 + l15) * 8];
      }
#pragma unroll
      for (int mt = 0; mt < 4; ++mt)
#pragma unroll
        for (int nt = 0; nt < 4; ++nt)
          acc[mt][nt] = __builtin_amdgcn_mfma_f32_16x16x32_bf16(
              afr[mt], bfr[nt], acc[mt][nt], 0, 0, 0);
    }
  }

#pragma unroll
  for (int nt = 0; nt < 4; ++nt) {
    int col = colBase + wn + nt * 16 + l15;
    float bv = flexload(bias, col, f);
    float s = 0.f, s2 = 0.f;
#pragma unroll
    for (int mt = 0; mt < 4; ++mt) {
#pragma unroll
      for (int r = 0; r < 4; ++r) {
        int row = rowBase + wm + mt * 16 + quad * 4 + r;
        if (row < M) {
          float v = acc[mt][nt][r] + bv;
          if (cf) ((float*)Cmat)[(size_t)row * Nc + col] = v;
          else ((u16*)Cmat)[(size_t)row * Nc + col] = f2bf(v);
          s += v;
          s2 += v * v;
        }
      }
    }
    if (stats) {
      s += __shfl_down(s, 32, 64);
      s += __shfl_down(s, 16, 64);
      s2 += __shfl_down(s2, 32, 64);
      s2 += __shfl_down(s2, 16, 64);
      if (quad == 0) {
        atomicAdd(&stats[col], s);
        atomicAdd(&stats[DIM + col], s2);
      }
    }
  }
}

// ---------------- SpMM with optional fused BN+ELU on the gathered values ----------------

__global__ __launch_bounds__(256) void k_spmm(
    const u16* __restrict__ x, u16* __restrict__ y,
    const int* __restrict__ row_start, const int* __restrict__ csr_src,
    const float* __restrict__ ns, const float* __restrict__ nd,
    const float* __restrict__ gb, int n) {
  int wid = (blockIdx.x * blockDim.x + threadIdx.x) >> 6;
  int lane = threadIdx.x & 63;
  if (wid >= n) return;
  int e0 = row_start[wid];
  int e1 = row_start[wid + 1];
  int c = lane * 4;
  float a0 = 0.f, a1 = 0.f, a2 = 0.f, a3 = 0.f;
  if (gb) {
    float g0 = gb[c], g1 = gb[c + 1], g2 = gb[c + 2], g3 = gb[c + 3];
    float b0 = gb[DIM + c], b1 = gb[DIM + c + 1], b2 = gb[DIM + c + 2], b3 = gb[DIM + c + 3];
    for (int e = e0; e < e1; ++e) {
      int s = csr_src[e];
      float w = ns[s];
      uint2 v = *(const uint2*)&x[(size_t)s * DIM + c];
      float x0 = g0 * bf2f((u16)(v.x & 0xffffu)) + b0;
      float x1 = g1 * bf2f((u16)(v.x >> 16)) + b1;
      float x2 = g2 * bf2f((u16)(v.y & 0xffffu)) + b2;
      float x3 = g3 * bf2f((u16)(v.y >> 16)) + b3;
      x0 = x0 > 0.f ? x0 : expm1f(x0);
      x1 = x1 > 0.f ? x1 : expm1f(x1);
      x2 = x2 > 0.f ? x2 : expm1f(x2);
      x3 = x3 > 0.f ? x3 : expm1f(x3);
      a0 += w * x0; a1 += w * x1; a2 += w * x2; a3 += w * x3;
    }
  } else {
    for (int e = e0; e < e1; ++e) {
      int s = csr_src[e];
      float w = ns[s];
      uint2 v = *(const uint2*)&x[(size_t)s * DIM + c];
      a0 += w * bf2f((u16)(v.x & 0xffffu));
      a1 += w * bf2f((u16)(v.x >> 16));
      a2 += w * bf2f((u16)(v.y & 0xffffu));
      a3 += w * bf2f((u16)(v.y >> 16));
    }
  }
  float wd = nd[wid];
  uint2 o;
  o.x = (unsigned)f2bf(a0 * wd) | ((unsigned)f2bf(a1 * wd) << 16);
  o.y = (unsigned)f2bf(a2 * wd) | ((unsigned)f2bf(a3 * wd) << 16);
  *(uint2*)&y[(size_t)wid * DIM + c] = o;
}

// ---------------- BN finalize ----------------

__global__ __launch_bounds__(256) void k_bnfin(const float* __restrict__ stats,
                                               const void* __restrict__ gamma,
                                               const void* __restrict__ beta,
                                               float* __restrict__ gb, int nrows,
                                               const int* __restrict__ dflag) {
  int f = dflag[0];
  int t = threadIdx.x;
  float inv_n = 1.0f / (float)nrows;
  float mu = stats[t] * inv_n;
  float var = stats[DIM + t] * inv_n - mu * mu;
  float rs = rsqrtf(var + 1e-5f);
  float g = flexload(gamma, t, f) * rs;
  float b = flexload(beta, t, f) - mu * g;
  gb[t] = g;
  gb[DIM + t] = b;
}

// ---------------- logits: out[M,40] = A[M,256] @ Wc + bc (MFMA, Wc in LDS) --------------

__global__ __launch_bounds__(256) void k_logits(
    const u16* __restrict__ A, const u16* __restrict__ Wct,
    const float* __restrict__ bcb, void* __restrict__ out,
    int M, const int* __restrict__ dflag) {
  __shared__ __align__(16) u16 As[64 * 128];     // 16 KB [kq8][m128][8]
  __shared__ __align__(16) u16 Wl[48 * WPAD];    // 24.75 KB
  const int f = dflag[0];
  const int tid = threadIdx.x;
  const int lane = tid & 63, wv = tid >> 6;
  const int quad = lane >> 4, l15 = lane & 15;
  const int rowBase = blockIdx.x * 128;

  for (int i = tid; i < 48 * WPAD / 2; i += 256)
    ((unsigned*)Wl)[i] = ((const unsigned*)Wct)[i];

  float4v acc[2][3];
#pragma unroll
  for (int a = 0; a < 2; ++a)
#pragma unroll
    for (int b = 0; b < 3; ++b) {
      acc[a][b][0] = 0.f; acc[a][b][1] = 0.f; acc[a][b][2] = 0.f; acc[a][b][3] = 0.f;
    }

  for (int k0 = 0; k0 < DIM; k0 += 64) {
    __syncthreads();
#pragma unroll
    for (int r = 0; r < 4; ++r) {
      int j = r * 256 + tid;
      int kq = j >> 7, m = j & 127;
      int grow = rowBase + m;
      if (grow >= M) grow = M - 1;
      async16(&A[(size_t)grow * DIM + k0 + kq * 8], &As[(size_t)j * 8]);
    }
    __syncthreads();
#pragma unroll
    for (int ks = 0; ks < 2; ++ks) {
      int kq = ks * 4 + quad;
      short8 afr[2], bfr[3];
#pragma unroll
      for (int t = 0; t < 2; ++t)
        afr[t] = *(const short8*)&As[(size_t)(kq * 128 + wv * 32 + t * 16 + l15) * 8];
#pragma unroll
      for (int t = 0; t < 3; ++t)
        bfr[t] = *(const short8*)&Wl[(size_t)(t * 16 + l15) * WPAD + k0 + kq * 8];
#pragma unroll
      for (int mt = 0; mt < 2; ++mt)
#pragma unroll
        for (int nt = 0; nt < 3; ++nt)
          acc[mt][nt] = __builtin_amdgcn_mfma_f32_16x16x32_bf16(
              afr[mt], bfr[nt], acc[mt][nt], 0, 0, 0);
    }
  }

#pragma unroll
  for (int nt = 0; nt < 3; ++nt) {
    int col = nt * 16 + l15;
    float bv = (col < NCLS) ? bcb[col] : 0.f;
#pragma unroll
    for (int mt = 0; mt < 2; ++mt) {
#pragma unroll
      for (int r = 0; r < 4; ++r) {
        int row = rowBase + wv * 32 + mt * 16 + quad * 4 + r;
        if (row < M && col < NCLS)
          flexstore(out, (size_t)N_NODES * DIM + (size_t)row * NCLS + col, f, acc[mt][nt][r] + bv);
      }
    }
  }
}

// ---------------- launch ----------------

extern "C" void kernel_launch(void* const* d_in, const int* in_sizes, int n_in,
                              void* d_out, int out_size, void* d_ws, size_t ws_size,
                              hipStream_t stream) {
  static const int EXP[15] = {51200000, 300000, 300000, 262144, 256, 65536, 256,
                              65536, 256, 65536, 256, 256, 256, 10240, 40};
  bool ok_sizes = (n_in == 15);
  if (ok_sizes)
    for (int i = 0; i < 15; ++i)
      if (in_sizes[i] != EXP[i]) ok_sizes = false;

  char* w = (char*)d_ws;
  size_t o = 0;
  auto take = [&](size_t bytes) {
    size_t r = o;
    o += (bytes + 255) & ~(size_t)255;
    return r;
  };
  size_t o_degf = take(N_NODES * 4);
  size_t o_degi = take(N_NODES * 4);
  size_t o_stat = take(1024 * 4);
  size_t zero_bytes = o;  // degf+degi+stats zeroed each call
  size_t o_flag = take(256);
  size_t o_gb = take(512 * 4);
  size_t o_ns = take(N_NODES * 4);
  size_t o_nd = take(N_NODES * 4);
  size_t o_rs = take((N_NODES + 1) * 4);
  size_t o_cur = take(N_NODES * 4);
  size_t o_csr = take(N_EDGES * 4);
  size_t o_wfc = take((size_t)FEAT * DIM * 2);
  size_t o_w1 = take(DIM * DIM * 2);
  size_t o_w2 = take(DIM * DIM * 2);
  size_t o_w3 = take(DIM * DIM * 2);
  size_t o_wc = take(48 * WPAD * 2);
  size_t o_bc = take(NCLS * 4);
  size_t o_xa = take((size_t)N_NODES * DIM * 2);
  size_t required = o;

  if (!ok_sizes || ws_size < required) {
    int* dflag0 = (int*)d_ws;
    float val = ok_sizes ? 1.0f : 2.0f;
    if (n_in > 0 && in_sizes[0] >= 2048)
      k_sniff<<<1, 256, 0, stream>>>((const u16*)d_in[0], dflag0);
    else
      k_setflag<<<1, 1, 0, stream>>>(dflag0, 0);
    k_filldiag<<<(out_size + 255) / 256, 256, 0, stream>>>(d_out, out_size, val, dflag0);
    return;
  }

  const void* feat = d_in[0];
  const int* src = (const int*)d_in[1];
  const int* dst = (const int*)d_in[2];
  const void* W_fc = d_in[3];
  const void* b_fc = d_in[4];
  const void* W1 = d_in[5];
  const void* b1 = d_in[6];
  const void* W2 = d_in[7];
  const void* b2 = d_in[8];
  const void* W3 = d_in[9];
  const void* b3 = d_in[10];
  const void* gamma = d_in[11];
  const void* beta = d_in[12];
  const void* W_lin = d_in[13];
  const void* b_lin = d_in[14];

  float* degf = (float*)(w + o_degf);
  int* degi = (int*)(w + o_degi);
  float* stats = (float*)(w + o_stat);
  int* dflag = (int*)(w + o_flag);
  float* gb = (float*)(w + o_gb);
  float* norm_s = (float*)(w + o_ns);
  float* norm_d = (float*)(w + o_nd);
  int* row_start = (int*)(w + o_rs);
  int* cursor = (int*)(w + o_cur);
  int* csr_src = (int*)(w + o_csr);
  u16* WtFc = (u16*)(w + o_wfc);
  u16* Wt1 = (u16*)(w + o_w1);
  u16* Wt2 = (u16*)(w + o_w2);
  u16* Wt3 = (u16*)(w + o_w3);
  u16* Wct = (u16*)(w + o_wc);
  float* bcb = (float*)(w + o_bc);
  u16* xA = (u16*)(w + o_xa);

  u16* ping = (u16*)d_out;  // d_out x-region doubles as internal bf16 ping buffer

  k_sniff<<<1, 256, 0, stream>>>((const u16*)feat, dflag);

  int zero_words = (int)(zero_bytes / 4);
  k_zero<<<(zero_words + 255) / 256, 256, 0, stream>>>((unsigned*)(w + 0), zero_words);
  k_deg<<<(N_EDGES + 255) / 256, 256, 0, stream>>>(src, dst, degf, degi, N_EDGES);
  k_norm<<<(N_NODES + 255) / 256, 256, 0, stream>>>(degf, degi, norm_s, norm_d, N_NODES);
  k_scan<<<1, 1024, 0, stream>>>(degi, row_start, cursor, N_NODES);
  k_scatter<<<(N_EDGES + 255) / 256, 256, 0, stream>>>(src, dst, cursor, csr_src, N_EDGES);
  k_transpose<<<((FEAT * DIM) + 255) / 256, 256, 0, stream>>>(W_fc, WtFc, FEAT, DIM, dflag);
  k_transpose<<<((DIM * DIM) + 255) / 256, 256, 0, stream>>>(W1, Wt1, DIM, DIM, dflag);
  k_transpose<<<((DIM * DIM) + 255) / 256, 256, 0, stream>>>(W2, Wt2, DIM, DIM, dflag);
  k_transpose<<<((DIM * DIM) + 255) / 256, 256, 0, stream>>>(W3, Wt3, DIM, DIM, dflag);
  k_combo<<<48, 256, 0, stream>>>(W3, W_lin, Wct, dflag);
  k_combobias<<<1, 64, 0, stream>>>(b3, W_lin, b_lin, bcb, dflag);

  dim3 gg((N_NODES + 127) / 128, DIM / 128);
  int gfc = (N_NODES + 127) / 128;

  // x0 = feat @ W_fc + b_fc -> ping
  k_gemm_fc<<<gfc, 256, 0, stream>>>(feat, WtFc, b_fc, ping, N_NODES, dflag);

  // layer 1 (BN stats fused into GEMM epilogue)
  k_spmm<<<(N_NODES + 3) / 4, 256, 0, stream>>>(ping, xA, row_start, csr_src, norm_s, norm_d, (const float*)nullptr, N_NODES);
  k_gemm_a<<<gg, 256, 0, stream>>>(xA, Wt1, b1, ping, N_NODES, DIM, DIM, 0, stats, dflag);
  k_bnfin<<<1, 256, 0, stream>>>(stats, gamma, beta, gb, N_NODES, dflag);

  // layer 2 (BN+ELU applied inside the gather)
  k_spmm<<<(N_NODES + 3) / 4, 256, 0, stream>>>(ping, xA, row_start, csr_src, norm_s, norm_d, gb, N_NODES);
  k_gemm_a<<<gg, 256, 0, stream>>>(xA, Wt2, b2, ping, N_NODES, DIM, DIM, 0, stats + 512, dflag);
  k_bnfin<<<1, 256, 0, stream>>>(stats + 512, gamma, beta, gb, N_NODES, dflag);

  // layer 3 -> output x (real output dtype)
  k_spmm<<<(N_NODES + 3) / 4, 256, 0, stream>>>(ping, xA, row_start, csr_src, norm_s, norm_d, gb, N_NODES);
  k_gemm_a<<<gg, 256, 0, stream>>>(xA, Wt3, b3, d_out, N_NODES, DIM, DIM, 1, (float*)nullptr, dflag);

  // logits = xA @ (W3 @ W_lin) + (b3 @ W_lin + b_lin)
  k_logits<<<gfc, 256, 0, stream>>>(xA, Wct, bcb, d_out, N_NODES, dflag);
}